// Round 17
// baseline (154.694 us; speedup 1.0000x reference)
//
#include <hip/hip_runtime.h>
#include <hip/hip_bf16.h>

typedef __bf16 bf16;
typedef __bf16 bf16x8 __attribute__((ext_vector_type(8)));
typedef __bf16 bf16x4 __attribute__((ext_vector_type(4)));
typedef float f32x4 __attribute__((ext_vector_type(4)));
typedef float f32x16 __attribute__((ext_vector_type(16)));
typedef unsigned int u32x2 __attribute__((ext_vector_type(2)));

#define EMBED 1024
#define NH 16
#define HD 64
#define BATCH 2
#define SEQ 2048
#define MTOK 4096
#define LOG2E 1.4426950408889634f

static __device__ __forceinline__ float fast_exp2(float x) {
#if __has_builtin(__builtin_amdgcn_exp2f)
  return __builtin_amdgcn_exp2f(x);
#else
  float r;
  asm("v_exp_f32 %0, %1" : "=v"(r) : "v"(x));
  return r;
#endif
}

static __device__ __forceinline__ f32x4 mfma16(bf16x8 a, bf16x8 b, f32x4 c) {
  return __builtin_amdgcn_mfma_f32_16x16x32_bf16(a, b, c, 0, 0, 0);
}
static __device__ __forceinline__ f32x16 mfma32(bf16x8 a, bf16x8 b, f32x16 c) {
  return __builtin_amdgcn_mfma_f32_32x32x16_bf16(a, b, c, 0, 0, 0);
}

static __device__ __forceinline__ void gld_lds16(const bf16* g, bf16* l) {
  __builtin_amdgcn_global_load_lds(
      (const __attribute__((address_space(1))) void*)g,
      (__attribute__((address_space(3))) void*)l, 16, 0, 0);
}

// ---------------- fused prep ----------------
// blocks [0,2048): x->bf16 ; [2048,2304): k_w^T ; [2304,2560): v_w^T ;
// [2560,2816): out_w^T ; [2816,3072): weff ; [3072,3088): beff
__global__ __launch_bounds__(256) void prep_kernel(
    const float* __restrict__ x, const float* __restrict__ qw,
    const float* __restrict__ qb, const float* __restrict__ kw,
    const float* __restrict__ vw, const float* __restrict__ ow,
    const float* __restrict__ ent, const float* __restrict__ phase,
    bf16* __restrict__ xb, bf16* __restrict__ wtall, bf16* __restrict__ wot,
    float* __restrict__ beff) {
  __shared__ float t0[64][65];
  __shared__ float t1[64][65];
  const int bb = blockIdx.x;
  const int tid = threadIdx.x;

  if (bb < 2048) {  // cvt x
    const int n4 = MTOK * EMBED / 4;
    int i = bb * 256 + tid;
    for (; i < n4; i += 2048 * 256) {
      f32x4 v = ((const f32x4*)x)[i];
      bf16x4 o;
      o[0] = (bf16)v[0]; o[1] = (bf16)v[1]; o[2] = (bf16)v[2]; o[3] = (bf16)v[3];
      ((bf16x4*)xb)[i] = o;
    }
    return;
  }
  if (bb < 2816) {  // transposes
    const int idx = (bb - 2048) & 255;
    const float* W = (bb < 2304) ? kw : (bb < 2560) ? vw : ow;
    bf16* Wt = (bb < 2304) ? (wtall + 1024 * 1024)
             : (bb < 2560) ? (wtall + 2 * 1024 * 1024) : wot;
    const int bc = (idx & 15) * 64;
    const int br = (idx >> 4) * 64;
#pragma unroll
    for (int j = 0; j < 16; j++) {
      int id2 = j * 256 + tid;
      int r = id2 >> 6, c = id2 & 63;
      t0[r][c] = W[(size_t)(br + r) * EMBED + bc + c];
    }
    __syncthreads();
#pragma unroll
    for (int j = 0; j < 16; j++) {
      int id2 = j * 256 + tid;
      int r = id2 >> 6, c = id2 & 63;
      Wt[(size_t)(bc + r) * EMBED + br + c] = (bf16)t0[c][r];
    }
    return;
  }
  if (bb < 3072) {  // weff: W_q_eff^T = (q_w @ blockdiag(E')*log2e)^T
    const int idx = bb - 2816;
    const int h = idx >> 4;
    const int ibase = (idx & 15) * 64;
#pragma unroll
    for (int j = 0; j < 16; j++) {
      int id2 = j * 256 + tid;
      int i = id2 >> 6, d = id2 & 63;
      t0[i][d] = qw[(size_t)(ibase + i) * EMBED + h * HD + d];
    }
#pragma unroll
    for (int j = 0; j < 16; j++) {
      int id2 = j * 256 + tid;
      int d = id2 >> 6, e = id2 & 63;
      float v = ent[((size_t)h * HD + d) * HD + e];
      if (d == e) { float cp = cosf(phase[h * HD + d]); v += cp * cp * 0.125f; }
      t1[d][e] = v * LOG2E;
    }
    __syncthreads();
    const int i = tid & 63;
    const int e0 = (tid >> 6) * 16;
    float s[16];
#pragma unroll
    for (int ee = 0; ee < 16; ee++) s[ee] = 0.f;
    for (int d = 0; d < 64; d++) {
      float qv = t0[i][d];
#pragma unroll
      for (int ee = 0; ee < 16; ee++) s[ee] += qv * t1[d][e0 + ee];
    }
#pragma unroll
    for (int ee = 0; ee < 16; ee++)
      wtall[(size_t)(h * HD + e0 + ee) * EMBED + ibase + i] = (bf16)s[ee];
    return;
  }
  // beff
  const int h = bb - 3072;
  if (tid < 64) {
    const int e = tid;
    float s = 0.f;
    for (int d = 0; d < 64; d++) {
      float v = ent[((size_t)h * HD + d) * HD + e];
      if (d == e) { float cp = cosf(phase[h * HD + d]); v += cp * cp * 0.125f; }
      s += qb[h * HD + d] * v;
    }
    beff[h * HD + e] = s * LOG2E;
  }
}

// ---------------- QKV GEMM (768 blocks, natural order) ----------------
__global__ __launch_bounds__(256, 4) void gemm_qkv_kernel(
    const bf16* __restrict__ A, const bf16* __restrict__ Bt,
    const float* __restrict__ bias_q, const float* __restrict__ bias_k,
    const float* __restrict__ bias_v,
    bf16* __restrict__ Qp, bf16* __restrict__ Kp, bf16* __restrict__ Vt) {
  const int tid = threadIdx.x;
  const int lane = tid & 63, w = tid >> 6;
  const int g = lane >> 4, r15 = lane & 15;
  const int wr = w >> 1, wc = w & 1;

  const int flat = blockIdx.x;
  const int bm = (flat & 31) * 128;
  const int bn = (flat >> 5) * 128;
  const int seg = bn >> 10;

  __shared__ bf16 sA[128 * 32];
  __shared__ bf16 sB[128 * 32];

  const int srow = tid >> 2;
  const int scol = (tid & 3) << 3;
  const bf16* aptr = A + (size_t)(bm + srow) * EMBED + scol;
  const bf16* bptr = Bt + (size_t)(bn + srow) * EMBED + scol;
  bf16* la = sA + tid * 8;
  bf16* lb = sB + tid * 8;

  if (seg == 2) {
    // ---- V body: unswapped mfma(af,bfv); transposed [b,h,d][s] store ----
    f32x4 acc[4][4];
#pragma unroll
    for (int m = 0; m < 4; m++)
#pragma unroll
      for (int n = 0; n < 4; n++) acc[m][n] = (f32x4){0.f, 0.f, 0.f, 0.f};

    for (int k0 = 0; k0 < EMBED; k0 += 32) {
      __syncthreads();
      gld_lds16(aptr + k0, la);
      gld_lds16(aptr + k0 + 64 * EMBED, la + 64 * 32);
      gld_lds16(bptr + k0, lb);
      gld_lds16(bptr + k0 + 64 * EMBED, lb + 64 * 32);
      __syncthreads();
      bf16x8 af[4], bfv[4];
#pragma unroll
      for (int m = 0; m < 4; m++)
        af[m] = *(const bf16x8*)&sA[(wr * 64 + m * 16 + r15) * 32 + g * 8];
#pragma unroll
      for (int n = 0; n < 4; n++)
        bfv[n] = *(const bf16x8*)&sB[(wc * 64 + n * 16 + r15) * 32 + g * 8];
#pragma unroll
      for (int m = 0; m < 4; m++)
#pragma unroll
        for (int n = 0; n < 4; n++) acc[m][n] = mfma16(af[m], bfv[n], acc[m][n]);
    }

    const int clb = (bn & 1023) + wc * 64;
    const int orow0 = bm + wr * 64;
#pragma unroll
    for (int n = 0; n < 4; n++) {
      const int cl = clb + n * 16 + r15;
      const float bias = bias_v[cl];
      const int hh = cl >> 6, d = cl & 63;
#pragma unroll
      for (int m = 0; m < 4; m++) {
        const int row0 = orow0 + m * 16 + g * 4;
        const int b = row0 >> 11, s = row0 & 2047;
        bf16x4 pk;
#pragma unroll
        for (int r = 0; r < 4; r++) pk[r] = (bf16)(acc[m][n][r] + bias);
        *(bf16x4*)(Vt + ((size_t)((b * NH + hh) * HD + d)) * SEQ + s) = pk;
      }
    }
  } else {
    // ---- Q/K body: swapped mfma(bfv,af); bf16x4 row-major stores ----
    f32x4 acc[4][4];
#pragma unroll
    for (int m = 0; m < 4; m++)
#pragma unroll
      for (int n = 0; n < 4; n++) acc[m][n] = (f32x4){0.f, 0.f, 0.f, 0.f};

    for (int k0 = 0; k0 < EMBED; k0 += 32) {
      __syncthreads();
      gld_lds16(aptr + k0, la);
      gld_lds16(aptr + k0 + 64 * EMBED, la + 64 * 32);
      gld_lds16(bptr + k0, lb);
      gld_lds16(bptr + k0 + 64 * EMBED, lb + 64 * 32);
      __syncthreads();
      bf16x8 af[4], bfv[4];
#pragma unroll
      for (int m = 0; m < 4; m++)
        af[m] = *(const bf16x8*)&sA[(wr * 64 + m * 16 + r15) * 32 + g * 8];
#pragma unroll
      for (int n = 0; n < 4; n++)
        bfv[n] = *(const bf16x8*)&sB[(wc * 64 + n * 16 + r15) * 32 + g * 8];
#pragma unroll
      for (int m = 0; m < 4; m++)
#pragma unroll
        for (int n = 0; n < 4; n++) acc[m][n] = mfma16(bfv[n], af[m], acc[m][n]);
    }

    const float* bias = seg ? bias_k : bias_q;
    bf16* dst = seg ? Kp : Qp;
    const int clb = (bn & 1023) + wc * 64;
#pragma unroll
    for (int n = 0; n < 4; n++) {
      const int cl4 = clb + n * 16 + g * 4;
      const f32x4 b4 = *(const f32x4*)&bias[cl4];
#pragma unroll
      for (int m = 0; m < 4; m++) {
        const int tr = bm + wr * 64 + m * 16 + r15;
        bf16x4 pk;
#pragma unroll
        for (int r = 0; r < 4; r++) pk[r] = (bf16)(acc[m][n][r] + b4[r]);
        *(bf16x4*)(dst + (size_t)tr * EMBED + cl4) = pk;
      }
    }
  }
}

// ---------------- out-proj GEMM: 64x128 tile, 512 blocks ----------------
__global__ __launch_bounds__(256, 4) void gemm_out_kernel(
    const bf16* __restrict__ A, const bf16* __restrict__ Bt,
    const float* __restrict__ bias_o, float* __restrict__ FO) {
  const int tid = threadIdx.x;
  const int lane = tid & 63, w = tid >> 6;
  const int g = lane >> 4, r15 = lane & 15;

  const int flat = blockIdx.x;
  const int bm = (flat & 63) * 64;
  const int bn = (flat >> 6) * 128;

  __shared__ bf16 sA[64 * 32];
  __shared__ bf16 sB[128 * 32];

  f32x4 acc[4][2];
#pragma unroll
  for (int m = 0; m < 4; m++)
#pragma unroll
    for (int n = 0; n < 2; n++) acc[m][n] = (f32x4){0.f, 0.f, 0.f, 0.f};

  const int srow = tid >> 2;
  const int scol = (tid & 3) << 3;
  const bf16* aptr = A + (size_t)(bm + srow) * EMBED + scol;  // srow 0..63
  const bf16* bptr = Bt + (size_t)(bn + srow) * EMBED + scol;
  bf16* la = sA + tid * 8;
  bf16* lb = sB + tid * 8;

  for (int k0 = 0; k0 < EMBED; k0 += 32) {
    __syncthreads();
    gld_lds16(aptr + k0, la);
    gld_lds16(bptr + k0, lb);
    gld_lds16(bptr + k0 + 64 * EMBED, lb + 64 * 32);
    __syncthreads();
    bf16x8 af[4], bfv[2];
#pragma unroll
    for (int m = 0; m < 4; m++)
      af[m] = *(const bf16x8*)&sA[(m * 16 + r15) * 32 + g * 8];
#pragma unroll
    for (int n = 0; n < 2; n++)
      bfv[n] = *(const bf16x8*)&sB[(w * 32 + n * 16 + r15) * 32 + g * 8];
#pragma unroll
    for (int m = 0; m < 4; m++)
#pragma unroll
      for (int n = 0; n < 2; n++) acc[m][n] = mfma16(bfv[n], af[m], acc[m][n]);
  }

#pragma unroll
  for (int n = 0; n < 2; n++) {
    const int cl4 = bn + w * 32 + n * 16 + g * 4;
    const f32x4 b4 = *(const f32x4*)&bias_o[cl4];
#pragma unroll
    for (int m = 0; m < 4; m++) {
      const int tr = bm + m * 16 + r15;
      *(f32x4*)(FO + (size_t)tr * EMBED + cl4) = acc[m][n] + b4;
    }
  }
}

// ---------------- flash attention (32x32 MFMA, KV-split, iter-pipelined) --
// 512 blocks (XCD-swizzled) x 512 thr = 8 waves. Waves 0-3: kv [0,1024),
// waves 4-7: kv [1024,2048); each wave owns 32 q-rows with its own (m,l,O).
// PIPELINED: QK(it+1) MFMAs issue BEFORE softmax(it) -- the VALU softmax
// chain overlaps in-flight MFMAs instead of depending on them. One barrier
// per iteration: stageK(it+2) mid-iter (target buffer's reads finished
// before the last barrier), stageV(it+2) post-barrier (PV reads done).
__global__ __launch_bounds__(512, 4) void flash_attn_kernel(
    const bf16* __restrict__ Qp, const bf16* __restrict__ Kp,
    const bf16* __restrict__ Vt, bf16* __restrict__ Op) {
  const int tid = threadIdx.x, lane = tid & 63, w = tid >> 6;
  const int q31 = lane & 31, hi = lane >> 5;
  const int half = w >> 2, wq = w & 3;
  // bijective XCD swizzle: 512 blocks = 8 xcd * 64; chunk = 4 bh * 16 qt
  const int flat = blockIdx.x;
  const int c = (flat & 7) * 64 + (flat >> 3);
  const int bh = c >> 4, qt = c & 15;
  const int b = bh >> 4, h = bh & 15;

  __shared__ char smem[65536];
  bf16* sKb = (bf16*)smem;             // [half*2+buf][4096] : 64 kv x 64 d
  bf16* sVb = (bf16*)(smem + 32768);   // [half*2+buf][4096] : 64 d  x 64 s

  const int g256 = tid & 255;          // within-half staging id
  const int strow = g256 >> 3;         // 0..31
  const int stcb = (g256 & 7) << 4;

  const char* kgbase = (const char*)(Kp + ((size_t)b * SEQ) * EMBED + h * HD);
  const char* vgbase = (const char*)(Vt + (size_t)bh * HD * SEQ);

  auto stageK = [&](int buf, int kv0) {
    bf16* kd = sKb + (size_t)(half * 2 + buf) * 4096 + g256 * 8;
#pragma unroll
    for (int i = 0; i < 2; i++) {
      const int row = i * 32 + strow;
      const int sb = stcb ^ ((row & 7) << 4);
      gld_lds16((const bf16*)(kgbase + (size_t)(kv0 + row) * (EMBED * 2) + sb),
                kd + i * 2048);
    }
  };
  auto stageV = [&](int buf, int kv0) {
    bf16* vd = sVb + (size_t)(half * 2 + buf) * 4096 + g256 * 8;
#pragma unroll
    for (int i = 0; i < 2; i++) {
      const int row = i * 32 + strow;
      const int sb = stcb ^ ((row & 7) << 4);
      gld_lds16((const bf16*)(vgbase + (size_t)row * (SEQ * 2) + (size_t)kv0 * 2 + sb),
                vd + i * 2048);
    }
  };

  const int kvbase = half * 1024;

  // Q B-operand frags: lane q31 = q-col, k-slice hi*8 within each 16-depth
  const int qbase = qt * 128 + wq * 32;
  const int qrow = qbase + q31;
  const bf16* qptr = Qp + ((size_t)(b * SEQ + qrow)) * EMBED + h * HD;
  bf16x8 aq[4];
#pragma unroll
  for (int ds = 0; ds < 4; ds++)
    aq[ds] = *(const bf16x8*)(qptr + ds * 16 + hi * 8);

  const int sz = (q31 & 7) << 4;
  int cofs[4];  // 128B-row chunk offsets: i*32 + hi*16, swizzled
#pragma unroll
  for (int i = 0; i < 4; i++) cofs[i] = ((i * 32 + hi * 16) ^ sz);

  f32x16 o0, o1;
#pragma unroll
  for (int i = 0; i < 16; i++) { o0[i] = 0.f; o1[i] = 0.f; }
  float mrow = -3.0e38f, lrow = 0.f;

  union B4 { bf16x4 v; unsigned int u[2]; };

  auto qk = [&](int it, f32x16& x0, f32x16& x1) {
    const char* kc = (const char*)(sKb + (size_t)(half * 2 + (it & 1)) * 4096)
                     + q31 * 128;
    f32x16 z0, z1;
#pragma unroll
    for (int i = 0; i < 16; i++) { z0[i] = 0.f; z1[i] = 0.f; }
    __builtin_amdgcn_s_setprio(1);
#pragma unroll
    for (int ds = 0; ds < 4; ds++) {
      bf16x8 bk0 = *(const bf16x8*)(kc + cofs[ds]);
      bf16x8 bk1 = *(const bf16x8*)(kc + 4096 + cofs[ds]);
      z0 = mfma32(bk0, aq[ds], z0);
      z1 = mfma32(bk1, aq[ds], z1);
    }
    __builtin_amdgcn_s_setprio(0);
    x0 = z0;
    x1 = z1;
  };

  // softmax(it) + PV(it) on the scores in (c0,c1)
  auto smpv = [&](int it, f32x16& c0, f32x16& c1) {
    // max via max3 tree (clang fuses fmaxf(fmaxf(a,b),c) -> v_max3)
    float t[11];
#pragma unroll
    for (int i = 0; i < 5; i++)
      t[i] = fmaxf(fmaxf(c0[3 * i], c0[3 * i + 1]), c0[3 * i + 2]);
    t[5] = fmaxf(fmaxf(c0[15], c1[0]), c1[1]);
#pragma unroll
    for (int i = 0; i < 4; i++)
      t[6 + i] = fmaxf(fmaxf(c1[2 + 3 * i], c1[3 + 3 * i]), c1[4 + 3 * i]);
    t[10] = fmaxf(c1[14], c1[15]);
    const float u0 = fmaxf(fmaxf(t[0], t[1]), t[2]);
    const float u1 = fmaxf(fmaxf(t[3], t[4]), t[5]);
    const float u2 = fmaxf(fmaxf(t[6], t[7]), t[8]);
    const float u3 = fmaxf(fmaxf(t[9], t[10]), u0);
    float mt = fmaxf(fmaxf(u1, u2), u3);
    {
      u32x2 sm = __builtin_amdgcn_permlane32_swap(__float_as_uint(mt),
                                                  __float_as_uint(mt), false, false);
      mt = fmaxf(__uint_as_float(sm.x), __uint_as_float(sm.y));
    }
    if (__any(mt > mrow + 8.f)) {
      const float mn = fmaxf(mrow, mt);
      const float al = fast_exp2(mrow - mn);
      mrow = mn;
      lrow *= al;
      o0 *= al;
      o1 *= al;
    }

    const char* vc = (const char*)(sVb + (size_t)(half * 2 + (it & 1)) * 4096)
                     + q31 * 128;
    float lsum = 0.f;
    __builtin_amdgcn_s_setprio(1);
#pragma unroll
    for (int kt = 0; kt < 4; kt++) {
      const f32x16& xs = (kt < 2) ? c0 : c1;
      const int jb = (kt & 1) * 2;
      B4 q0, q1;
#pragma unroll
      for (int r = 0; r < 4; r++) {
        float pa = fast_exp2(xs[4 * jb + r] - mrow);
        float pb = fast_exp2(xs[4 * (jb + 1) + r] - mrow);
        lsum += pa + pb;
        q0.v[r] = (bf16)pa;
        q1.v[r] = (bf16)pb;
      }
      u32x2 p0 = __builtin_amdgcn_permlane32_swap(q0.u[0], q1.u[0], false, false);
      u32x2 p1 = __builtin_amdgcn_permlane32_swap(q0.u[1], q1.u[1], false, false);
      union { unsigned int u[4]; bf16x8 v; } f;
      f.u[0] = p0.x; f.u[1] = p1.x; f.u[2] = p0.y; f.u[3] = p1.y;
      bf16x8 av0 = *(const bf16x8*)(vc + cofs[kt]);
      bf16x8 av1 = *(const bf16x8*)(vc + 4096 + cofs[kt]);
      o0 = mfma32(av0, f.v, o0);
      o1 = mfma32(av1, f.v, o1);
    }
    __builtin_amdgcn_s_setprio(0);
    {
      u32x2 ss = __builtin_amdgcn_permlane32_swap(__float_as_uint(lsum),
                                                  __float_as_uint(lsum), false, false);
      lrow += __uint_as_float(ss.x) + __uint_as_float(ss.y);  // own + partner
    }
  };

  // ---- prologue: stage iters 0,1; QK(0) ----
  stageK(0, kvbase);
  stageV(0, kvbase);
  stageK(1, kvbase + 64);
  stageV(1, kvbase + 64);
  asm volatile("s_waitcnt vmcnt(0)" ::: "memory");
  __builtin_amdgcn_s_barrier();

  f32x16 sa0, sa1, sb0, sb1;
  qk(0, sa0, sa1);
  __builtin_amdgcn_s_barrier();  // QK(0) reads done before stageK(2) -> buf0

  // ---- main loop: 16 iterations, pair-unrolled (named score states) ----
#pragma unroll
  for (int ii = 0; ii < 8; ii++) {
    {
      const int it = 2 * ii;
      if (it < 15) qk(it + 1, sb0, sb1);
      if (it < 14) stageK(it & 1, kvbase + (it + 2) * 64);
      smpv(it, sa0, sa1);
      asm volatile("s_waitcnt vmcnt(0)" ::: "memory");
      __builtin_amdgcn_s_barrier();
      if (it < 14) stageV(it & 1, kvbase + (it + 2) * 64);
    }
    {
      const int it = 2 * ii + 1;
      if (it < 15) qk(it + 1, sa0, sa1);
      if (it < 14) stageK(it & 1, kvbase + (it + 2) * 64);
      smpv(it, sb0, sb1);
      asm volatile("s_waitcnt vmcnt(0)" ::: "memory");
      __builtin_amdgcn_s_barrier();
      if (it < 14) stageV(it & 1, kvbase + (it + 2) * 64);
    }
  }

  // ---- merge halves through reused LDS ----
  float* shO = (float*)smem;             // [4][64][33]
  float* shML = (float*)(smem + 33792);  // [4][64][2]
  if (half == 1) {
    float* o = shO + (size_t)(wq * 64 + lane) * 33;
#pragma unroll
    for (int i = 0; i < 16; i++) { o[i] = o0[i]; o[16 + i] = o1[i]; }
    shML[(wq * 64 + lane) * 2] = mrow;
    shML[(wq * 64 + lane) * 2 + 1] = lrow;
  }
  __syncthreads();
  if (half == 0) {
    const float* o = shO + (size_t)(wq * 64 + lane) * 33;
    const float mB = shML[(wq * 64 + lane) * 2];
    const float lB = shML[(wq * 64 + lane) * 2 + 1];
    const float M = fmaxf(mrow, mB);
    const float wA = fast_exp2(mrow - M), wB = fast_exp2(mB - M);
    const float inv = 1.f / (lrow * wA + lB * wB);
    const float fA = wA * inv, fB = wB * inv;

    // O[d][q]: lane q31 owns q-col; d = 8*j + 4*hi + r (o0), +32 (o1)
    bf16* obase = Op + ((size_t)(b * SEQ + qrow)) * EMBED + h * HD;
#pragma unroll
    for (int j = 0; j < 4; j++) {
      bf16x4 st;
#pragma unroll
      for (int r = 0; r < 4; r++)
        st[r] = (bf16)(o0[4 * j + r] * fA + o[4 * j + r] * fB);
      *(bf16x4*)(obase + 8 * j + 4 * hi) = st;
    }
#pragma unroll
    for (int j = 0; j < 4; j++) {
      bf16x4 st;
#pragma unroll
      for (int r = 0; r < 4; r++)
        st[r] = (bf16)(o1[4 * j + r] * fA + o[16 + 4 * j + r] * fB);
      *(bf16x4*)(obase + 32 + 8 * j + 4 * hi) = st;
    }
  }
}

// ---------------- launch ----------------
extern "C" void kernel_launch(void* const* d_in, const int* in_sizes, int n_in,
                              void* d_out, int out_size, void* d_ws, size_t ws_size,
                              hipStream_t stream) {
  const float* x     = (const float*)d_in[0];
  const float* q_w   = (const float*)d_in[1];
  const float* q_b   = (const float*)d_in[2];
  const float* k_w   = (const float*)d_in[3];
  const float* k_b   = (const float*)d_in[4];
  const float* v_w   = (const float*)d_in[5];
  const float* v_b   = (const float*)d_in[6];
  const float* phase = (const float*)d_in[7];
  const float* ent   = (const float*)d_in[8];
  const float* out_w = (const float*)d_in[9];
  const float* out_b = (const float*)d_in[10];
  float* out = (float*)d_out;

  char* ws = (char*)d_ws;
  bf16* xb    = (bf16*)(ws + 0);          // 8388608 B, [B,S,E] bf16; reused as attn out
  bf16* wtall = (bf16*)(ws + 8388608);    // 6291456 B, [3072][1024] bf16 (Qeff|K|V)
  bf16* wot   = (bf16*)(ws + 14680064);   // 2097152 B, out_w^T bf16
  float* beff = (float*)(ws + 16777216);  // 4096 B
  bf16* Qp    = (bf16*)(ws + 16781312);   // 8388608 B
  bf16* Kp    = (bf16*)(ws + 25169920);   // 8388608 B
  bf16* Vt    = (bf16*)(ws + 33558528);   // 8388608 B, [b,h,d,s]
  (void)in_sizes; (void)n_in; (void)out_size; (void)ws_size;

  prep_kernel<<<3088, 256, 0, stream>>>(x, q_w, q_b, k_w, v_w, out_w, ent, phase,
                                        xb, wtall, wot, beff);

  gemm_qkv_kernel<<<768, 256, 0, stream>>>(
      xb, wtall, beff, k_b, v_b, Qp, Kp, Vt);

  flash_attn_kernel<<<512, 512, 0, stream>>>(Qp, Kp, Vt, xb);

  gemm_out_kernel<<<512, 256, 0, stream>>>(xb, wot, out_b, out);
}

// Round 18
// 138.089 us; speedup vs baseline: 1.1203x; 1.1203x over previous
//
#include <hip/hip_runtime.h>
#include <hip/hip_bf16.h>

typedef __bf16 bf16;
typedef __bf16 bf16x8 __attribute__((ext_vector_type(8)));
typedef __bf16 bf16x4 __attribute__((ext_vector_type(4)));
typedef float f32x4 __attribute__((ext_vector_type(4)));
typedef float f32x16 __attribute__((ext_vector_type(16)));
typedef unsigned int u32x2 __attribute__((ext_vector_type(2)));

#define EMBED 1024
#define NH 16
#define HD 64
#define BATCH 2
#define SEQ 2048
#define MTOK 4096
#define LOG2E 1.4426950408889634f

static __device__ __forceinline__ float fast_exp2(float x) {
#if __has_builtin(__builtin_amdgcn_exp2f)
  return __builtin_amdgcn_exp2f(x);
#else
  float r;
  asm("v_exp_f32 %0, %1" : "=v"(r) : "v"(x));
  return r;
#endif
}

static __device__ __forceinline__ f32x4 mfma16(bf16x8 a, bf16x8 b, f32x4 c) {
  return __builtin_amdgcn_mfma_f32_16x16x32_bf16(a, b, c, 0, 0, 0);
}
static __device__ __forceinline__ f32x16 mfma32(bf16x8 a, bf16x8 b, f32x16 c) {
  return __builtin_amdgcn_mfma_f32_32x32x16_bf16(a, b, c, 0, 0, 0);
}

static __device__ __forceinline__ void gld_lds16(const bf16* g, bf16* l) {
  __builtin_amdgcn_global_load_lds(
      (const __attribute__((address_space(1))) void*)g,
      (__attribute__((address_space(3))) void*)l, 16, 0, 0);
}

// ---------------- fused prep ----------------
// blocks [0,2048): x->bf16 ; [2048,2304): k_w^T ; [2304,2560): v_w^T ;
// [2560,2816): out_w^T ; [2816,3072): weff ; [3072,3088): beff
__global__ __launch_bounds__(256) void prep_kernel(
    const float* __restrict__ x, const float* __restrict__ qw,
    const float* __restrict__ qb, const float* __restrict__ kw,
    const float* __restrict__ vw, const float* __restrict__ ow,
    const float* __restrict__ ent, const float* __restrict__ phase,
    bf16* __restrict__ xb, bf16* __restrict__ wtall, bf16* __restrict__ wot,
    float* __restrict__ beff) {
  __shared__ float t0[64][65];
  __shared__ float t1[64][65];
  const int bb = blockIdx.x;
  const int tid = threadIdx.x;

  if (bb < 2048) {  // cvt x
    const int n4 = MTOK * EMBED / 4;
    int i = bb * 256 + tid;
    for (; i < n4; i += 2048 * 256) {
      f32x4 v = ((const f32x4*)x)[i];
      bf16x4 o;
      o[0] = (bf16)v[0]; o[1] = (bf16)v[1]; o[2] = (bf16)v[2]; o[3] = (bf16)v[3];
      ((bf16x4*)xb)[i] = o;
    }
    return;
  }
  if (bb < 2816) {  // transposes
    const int idx = (bb - 2048) & 255;
    const float* W = (bb < 2304) ? kw : (bb < 2560) ? vw : ow;
    bf16* Wt = (bb < 2304) ? (wtall + 1024 * 1024)
             : (bb < 2560) ? (wtall + 2 * 1024 * 1024) : wot;
    const int bc = (idx & 15) * 64;
    const int br = (idx >> 4) * 64;
#pragma unroll
    for (int j = 0; j < 16; j++) {
      int id2 = j * 256 + tid;
      int r = id2 >> 6, c = id2 & 63;
      t0[r][c] = W[(size_t)(br + r) * EMBED + bc + c];
    }
    __syncthreads();
#pragma unroll
    for (int j = 0; j < 16; j++) {
      int id2 = j * 256 + tid;
      int r = id2 >> 6, c = id2 & 63;
      Wt[(size_t)(bc + r) * EMBED + br + c] = (bf16)t0[c][r];
    }
    return;
  }
  if (bb < 3072) {  // weff: W_q_eff^T = (q_w @ blockdiag(E')*log2e)^T
    const int idx = bb - 2816;
    const int h = idx >> 4;
    const int ibase = (idx & 15) * 64;
#pragma unroll
    for (int j = 0; j < 16; j++) {
      int id2 = j * 256 + tid;
      int i = id2 >> 6, d = id2 & 63;
      t0[i][d] = qw[(size_t)(ibase + i) * EMBED + h * HD + d];
    }
#pragma unroll
    for (int j = 0; j < 16; j++) {
      int id2 = j * 256 + tid;
      int d = id2 >> 6, e = id2 & 63;
      float v = ent[((size_t)h * HD + d) * HD + e];
      if (d == e) { float cp = cosf(phase[h * HD + d]); v += cp * cp * 0.125f; }
      t1[d][e] = v * LOG2E;
    }
    __syncthreads();
    const int i = tid & 63;
    const int e0 = (tid >> 6) * 16;
    float s[16];
#pragma unroll
    for (int ee = 0; ee < 16; ee++) s[ee] = 0.f;
    for (int d = 0; d < 64; d++) {
      float qv = t0[i][d];
#pragma unroll
      for (int ee = 0; ee < 16; ee++) s[ee] += qv * t1[d][e0 + ee];
    }
#pragma unroll
    for (int ee = 0; ee < 16; ee++)
      wtall[(size_t)(h * HD + e0 + ee) * EMBED + ibase + i] = (bf16)s[ee];
    return;
  }
  // beff
  const int h = bb - 3072;
  if (tid < 64) {
    const int e = tid;
    float s = 0.f;
    for (int d = 0; d < 64; d++) {
      float v = ent[((size_t)h * HD + d) * HD + e];
      if (d == e) { float cp = cosf(phase[h * HD + d]); v += cp * cp * 0.125f; }
      s += qb[h * HD + d] * v;
    }
    beff[h * HD + e] = s * LOG2E;
  }
}

// ---------------- QKV GEMM (768 blocks, natural order) ----------------
__global__ __launch_bounds__(256, 4) void gemm_qkv_kernel(
    const bf16* __restrict__ A, const bf16* __restrict__ Bt,
    const float* __restrict__ bias_q, const float* __restrict__ bias_k,
    const float* __restrict__ bias_v,
    bf16* __restrict__ Qp, bf16* __restrict__ Kp, bf16* __restrict__ Vt) {
  const int tid = threadIdx.x;
  const int lane = tid & 63, w = tid >> 6;
  const int g = lane >> 4, r15 = lane & 15;
  const int wr = w >> 1, wc = w & 1;

  const int flat = blockIdx.x;
  const int bm = (flat & 31) * 128;
  const int bn = (flat >> 5) * 128;
  const int seg = bn >> 10;

  __shared__ bf16 sA[128 * 32];
  __shared__ bf16 sB[128 * 32];

  const int srow = tid >> 2;
  const int scol = (tid & 3) << 3;
  const bf16* aptr = A + (size_t)(bm + srow) * EMBED + scol;
  const bf16* bptr = Bt + (size_t)(bn + srow) * EMBED + scol;
  bf16* la = sA + tid * 8;
  bf16* lb = sB + tid * 8;

  if (seg == 2) {
    // ---- V body: unswapped mfma(af,bfv); transposed [b,h,d][s] store ----
    f32x4 acc[4][4];
#pragma unroll
    for (int m = 0; m < 4; m++)
#pragma unroll
      for (int n = 0; n < 4; n++) acc[m][n] = (f32x4){0.f, 0.f, 0.f, 0.f};

    for (int k0 = 0; k0 < EMBED; k0 += 32) {
      __syncthreads();
      gld_lds16(aptr + k0, la);
      gld_lds16(aptr + k0 + 64 * EMBED, la + 64 * 32);
      gld_lds16(bptr + k0, lb);
      gld_lds16(bptr + k0 + 64 * EMBED, lb + 64 * 32);
      __syncthreads();
      bf16x8 af[4], bfv[4];
#pragma unroll
      for (int m = 0; m < 4; m++)
        af[m] = *(const bf16x8*)&sA[(wr * 64 + m * 16 + r15) * 32 + g * 8];
#pragma unroll
      for (int n = 0; n < 4; n++)
        bfv[n] = *(const bf16x8*)&sB[(wc * 64 + n * 16 + r15) * 32 + g * 8];
#pragma unroll
      for (int m = 0; m < 4; m++)
#pragma unroll
        for (int n = 0; n < 4; n++) acc[m][n] = mfma16(af[m], bfv[n], acc[m][n]);
    }

    const int clb = (bn & 1023) + wc * 64;
    const int orow0 = bm + wr * 64;
#pragma unroll
    for (int n = 0; n < 4; n++) {
      const int cl = clb + n * 16 + r15;
      const float bias = bias_v[cl];
      const int hh = cl >> 6, d = cl & 63;
#pragma unroll
      for (int m = 0; m < 4; m++) {
        const int row0 = orow0 + m * 16 + g * 4;
        const int b = row0 >> 11, s = row0 & 2047;
        bf16x4 pk;
#pragma unroll
        for (int r = 0; r < 4; r++) pk[r] = (bf16)(acc[m][n][r] + bias);
        *(bf16x4*)(Vt + ((size_t)((b * NH + hh) * HD + d)) * SEQ + s) = pk;
      }
    }
  } else {
    // ---- Q/K body: swapped mfma(bfv,af); bf16x4 row-major stores ----
    f32x4 acc[4][4];
#pragma unroll
    for (int m = 0; m < 4; m++)
#pragma unroll
      for (int n = 0; n < 4; n++) acc[m][n] = (f32x4){0.f, 0.f, 0.f, 0.f};

    for (int k0 = 0; k0 < EMBED; k0 += 32) {
      __syncthreads();
      gld_lds16(aptr + k0, la);
      gld_lds16(aptr + k0 + 64 * EMBED, la + 64 * 32);
      gld_lds16(bptr + k0, lb);
      gld_lds16(bptr + k0 + 64 * EMBED, lb + 64 * 32);
      __syncthreads();
      bf16x8 af[4], bfv[4];
#pragma unroll
      for (int m = 0; m < 4; m++)
        af[m] = *(const bf16x8*)&sA[(wr * 64 + m * 16 + r15) * 32 + g * 8];
#pragma unroll
      for (int n = 0; n < 4; n++)
        bfv[n] = *(const bf16x8*)&sB[(wc * 64 + n * 16 + r15) * 32 + g * 8];
#pragma unroll
      for (int m = 0; m < 4; m++)
#pragma unroll
        for (int n = 0; n < 4; n++) acc[m][n] = mfma16(bfv[n], af[m], acc[m][n]);
    }

    const float* bias = seg ? bias_k : bias_q;
    bf16* dst = seg ? Kp : Qp;
    const int clb = (bn & 1023) + wc * 64;
#pragma unroll
    for (int n = 0; n < 4; n++) {
      const int cl4 = clb + n * 16 + g * 4;
      const f32x4 b4 = *(const f32x4*)&bias[cl4];
#pragma unroll
      for (int m = 0; m < 4; m++) {
        const int tr = bm + wr * 64 + m * 16 + r15;
        bf16x4 pk;
#pragma unroll
        for (int r = 0; r < 4; r++) pk[r] = (bf16)(acc[m][n][r] + b4[r]);
        *(bf16x4*)(dst + (size_t)tr * EMBED + cl4) = pk;
      }
    }
  }
}

// ---------------- out-proj GEMM: 64x128 tile, 512 blocks ----------------
__global__ __launch_bounds__(256, 4) void gemm_out_kernel(
    const bf16* __restrict__ A, const bf16* __restrict__ Bt,
    const float* __restrict__ bias_o, float* __restrict__ FO) {
  const int tid = threadIdx.x;
  const int lane = tid & 63, w = tid >> 6;
  const int g = lane >> 4, r15 = lane & 15;

  const int flat = blockIdx.x;
  const int bm = (flat & 63) * 64;
  const int bn = (flat >> 6) * 128;

  __shared__ bf16 sA[64 * 32];
  __shared__ bf16 sB[128 * 32];

  f32x4 acc[4][2];
#pragma unroll
  for (int m = 0; m < 4; m++)
#pragma unroll
    for (int n = 0; n < 2; n++) acc[m][n] = (f32x4){0.f, 0.f, 0.f, 0.f};

  const int srow = tid >> 2;
  const int scol = (tid & 3) << 3;
  const bf16* aptr = A + (size_t)(bm + srow) * EMBED + scol;  // srow 0..63
  const bf16* bptr = Bt + (size_t)(bn + srow) * EMBED + scol;
  bf16* la = sA + tid * 8;
  bf16* lb = sB + tid * 8;

  for (int k0 = 0; k0 < EMBED; k0 += 32) {
    __syncthreads();
    gld_lds16(aptr + k0, la);
    gld_lds16(bptr + k0, lb);
    gld_lds16(bptr + k0 + 64 * EMBED, lb + 64 * 32);
    __syncthreads();
    bf16x8 af[4], bfv[2];
#pragma unroll
    for (int m = 0; m < 4; m++)
      af[m] = *(const bf16x8*)&sA[(m * 16 + r15) * 32 + g * 8];
#pragma unroll
    for (int n = 0; n < 2; n++)
      bfv[n] = *(const bf16x8*)&sB[(w * 32 + n * 16 + r15) * 32 + g * 8];
#pragma unroll
    for (int m = 0; m < 4; m++)
#pragma unroll
      for (int n = 0; n < 2; n++) acc[m][n] = mfma16(bfv[n], af[m], acc[m][n]);
  }

#pragma unroll
  for (int n = 0; n < 2; n++) {
    const int cl4 = bn + w * 32 + n * 16 + g * 4;
    const f32x4 b4 = *(const f32x4*)&bias_o[cl4];
#pragma unroll
    for (int m = 0; m < 4; m++) {
      const int tr = bm + m * 16 + r15;
      *(f32x4*)(FO + (size_t)tr * EMBED + cl4) = acc[m][n] + b4;
    }
  }
}

// ---------------- flash attention (32x32 MFMA, half-tile pipelined) ------
// 512 blocks (XCD-swizzled) x 512 thr = 8 waves; KV-split halves as before.
// Pipeline at 32-kv granularity: QK(half1,cur)->sB overlaps smpv(half0,sA);
// QK(half0,next)->sA overlaps smpv(half1,sB). Only TWO f32x16 score states
// live (no spill). Macros, named vars only (rule #20).

// Z += K[rows SEL*32+q31][:] . Q  (4 MFMAs)
#define QK_HALF(CUR, SEL, Z)                                                   \
  do {                                                                         \
    const char* kc_ = (const char*)(sKb + (size_t)(half * 2 + (CUR)) * 4096) + \
                      q31 * 128 + (SEL) * 4096;                                \
    __builtin_amdgcn_s_setprio(1);                                             \
    _Pragma("unroll") for (int ds_ = 0; ds_ < 4; ds_++) {                      \
      bf16x8 bk_ = *(const bf16x8*)(kc_ + cofs[ds_]);                          \
      Z = mfma32(bk_, aq[ds_], Z);                                             \
    }                                                                          \
    __builtin_amdgcn_s_setprio(0);                                             \
  } while (0)

// softmax + PV on score state S (covers kv SEL*32 .. +31 of buffer CUR)
#define SMPV_HALF(CUR, SEL, S)                                                 \
  do {                                                                         \
    float t0_ = fmaxf(fmaxf(S[0], S[1]), S[2]);                                \
    float t1_ = fmaxf(fmaxf(S[3], S[4]), S[5]);                                \
    float t2_ = fmaxf(fmaxf(S[6], S[7]), S[8]);                                \
    float t3_ = fmaxf(fmaxf(S[9], S[10]), S[11]);                              \
    float t4_ = fmaxf(fmaxf(S[12], S[13]), S[14]);                             \
    float u0_ = fmaxf(fmaxf(t0_, t1_), t2_);                                   \
    float u1_ = fmaxf(fmaxf(t3_, t4_), S[15]);                                 \
    float mt_ = fmaxf(u0_, u1_);                                               \
    u32x2 sm_ = __builtin_amdgcn_permlane32_swap(                              \
        __float_as_uint(mt_), __float_as_uint(mt_), false, false);             \
    mt_ = fmaxf(__uint_as_float(sm_.x), __uint_as_float(sm_.y));               \
    if (__any(mt_ > mrow + 8.f)) {                                             \
      const float mn_ = fmaxf(mrow, mt_);                                      \
      const float al_ = fast_exp2(mrow - mn_);                                 \
      mrow = mn_;                                                              \
      lrow *= al_;                                                             \
      o0 *= al_;                                                               \
      o1 *= al_;                                                               \
    }                                                                          \
    const char* vc_ = (const char*)(sVb + (size_t)(half * 2 + (CUR)) * 4096) + \
                      q31 * 128;                                               \
    float lsum_ = 0.f;                                                         \
    _Pragma("unroll") for (int kk_ = 0; kk_ < 2; kk_++) {                      \
      const int jb_ = kk_ * 2;                                                 \
      B4 q0_, q1_;                                                             \
      _Pragma("unroll") for (int r_ = 0; r_ < 4; r_++) {                       \
        float pa_ = fast_exp2(S[4 * jb_ + r_] - mrow);                         \
        float pb_ = fast_exp2(S[4 * jb_ + 4 + r_] - mrow);                     \
        lsum_ += pa_ + pb_;                                                    \
        q0_.v[r_] = (bf16)pa_;                                                 \
        q1_.v[r_] = (bf16)pb_;                                                 \
      }                                                                        \
      u32x2 p0_ = __builtin_amdgcn_permlane32_swap(q0_.u[0], q1_.u[0],         \
                                                   false, false);              \
      u32x2 p1_ = __builtin_amdgcn_permlane32_swap(q0_.u[1], q1_.u[1],         \
                                                   false, false);              \
      union { unsigned int u[4]; bf16x8 v; } f_;                               \
      f_.u[0] = p0_.x; f_.u[1] = p1_.x; f_.u[2] = p0_.y; f_.u[3] = p1_.y;      \
      bf16x8 av0_ = *(const bf16x8*)(vc_ + cofs[2 * (SEL) + kk_]);             \
      bf16x8 av1_ = *(const bf16x8*)(vc_ + 4096 + cofs[2 * (SEL) + kk_]);      \
      __builtin_amdgcn_s_setprio(1);                                           \
      o0 = mfma32(av0_, f_.v, o0);                                             \
      o1 = mfma32(av1_, f_.v, o1);                                             \
      __builtin_amdgcn_s_setprio(0);                                           \
    }                                                                          \
    u32x2 ss_ = __builtin_amdgcn_permlane32_swap(                              \
        __float_as_uint(lsum_), __float_as_uint(lsum_), false, false);         \
    lrow += __uint_as_float(ss_.x) + __uint_as_float(ss_.y);                   \
  } while (0)

__global__ __launch_bounds__(512, 4) void flash_attn_kernel(
    const bf16* __restrict__ Qp, const bf16* __restrict__ Kp,
    const bf16* __restrict__ Vt, bf16* __restrict__ Op) {
  const int tid = threadIdx.x, lane = tid & 63, w = tid >> 6;
  const int q31 = lane & 31, hi = lane >> 5;
  const int half = w >> 2, wq = w & 3;
  // bijective XCD swizzle: 512 blocks = 8 xcd * 64; chunk = 4 bh * 16 qt
  const int flat = blockIdx.x;
  const int c = (flat & 7) * 64 + (flat >> 3);
  const int bh = c >> 4, qt = c & 15;
  const int b = bh >> 4, h = bh & 15;

  __shared__ char smem[65536];
  bf16* sKb = (bf16*)smem;             // [half*2+buf][4096] : 64 kv x 64 d
  bf16* sVb = (bf16*)(smem + 32768);   // [half*2+buf][4096] : 64 d  x 64 s

  const int g256 = tid & 255;          // within-half staging id
  const int strow = g256 >> 3;         // 0..31
  const int stcb = (g256 & 7) << 4;

  const char* kgbase = (const char*)(Kp + ((size_t)b * SEQ) * EMBED + h * HD);
  const char* vgbase = (const char*)(Vt + (size_t)bh * HD * SEQ);

  auto stageK = [&](int buf, int kv0) {
    bf16* kd = sKb + (size_t)(half * 2 + buf) * 4096 + g256 * 8;
#pragma unroll
    for (int i = 0; i < 2; i++) {
      const int row = i * 32 + strow;
      const int sb = stcb ^ ((row & 7) << 4);
      gld_lds16((const bf16*)(kgbase + (size_t)(kv0 + row) * (EMBED * 2) + sb),
                kd + i * 2048);
    }
  };
  auto stageV = [&](int buf, int kv0) {
    bf16* vd = sVb + (size_t)(half * 2 + buf) * 4096 + g256 * 8;
#pragma unroll
    for (int i = 0; i < 2; i++) {
      const int row = i * 32 + strow;
      const int sb = stcb ^ ((row & 7) << 4);
      gld_lds16((const bf16*)(vgbase + (size_t)row * (SEQ * 2) + (size_t)kv0 * 2 + sb),
                vd + i * 2048);
    }
  };

  const int kvbase = half * 1024;

  // Q B-operand frags: lane q31 = q-col, k-slice hi*8 within each 16-depth
  const int qbase = qt * 128 + wq * 32;
  const int qrow = qbase + q31;
  const bf16* qptr = Qp + ((size_t)(b * SEQ + qrow)) * EMBED + h * HD;
  bf16x8 aq[4];
#pragma unroll
  for (int ds = 0; ds < 4; ds++)
    aq[ds] = *(const bf16x8*)(qptr + ds * 16 + hi * 8);

  const int sz = (q31 & 7) << 4;
  int cofs[4];  // 128B-row chunk offsets: i*32 + hi*16, swizzled
#pragma unroll
  for (int i = 0; i < 4; i++) cofs[i] = ((i * 32 + hi * 16) ^ sz);

  f32x16 o0, o1;
#pragma unroll
  for (int i = 0; i < 16; i++) { o0[i] = 0.f; o1[i] = 0.f; }
  float mrow = -3.0e38f, lrow = 0.f;

  union B4 { bf16x4 v; unsigned int u[2]; };

  // ---- prologue ----
  stageK(0, kvbase);
  stageV(0, kvbase);
  stageK(1, kvbase + 64);
  stageV(1, kvbase + 64);
  asm volatile("s_waitcnt vmcnt(0)" ::: "memory");
  __builtin_amdgcn_s_barrier();

  f32x16 sA, sB;
#pragma unroll
  for (int i = 0; i < 16; i++) sA[i] = 0.f;
  QK_HALF(0, 0, sA);

#pragma unroll
  for (int it = 0; it < 16; ++it) {
    const int cur = it & 1;
    // (1) QK half1 of cur -> sB  (finishes this wave's K-cur reads)
#pragma unroll
    for (int i = 0; i < 16; i++) sB[i] = 0.f;
    QK_HALF(cur, 1, sB);
    // (2) softmax+PV on sA (kv half0 of cur) -- overlaps (1)'s MFMAs
    SMPV_HALF(cur, 0, sA);
    // (3) next buffer fully staged & all waves synced
    asm volatile("s_waitcnt vmcnt(0)" ::: "memory");
    __builtin_amdgcn_s_barrier();
    // (4) QK half0 of NEXT buffer -> sA
    if (it < 15) {
#pragma unroll
      for (int i = 0; i < 16; i++) sA[i] = 0.f;
      QK_HALF(cur ^ 1, 0, sA);
    }
    // (5) softmax+PV on sB (kv half1 of cur; last reads of buffer cur)
    SMPV_HALF(cur, 1, sB);
    // (6) all waves done reading cur
    __builtin_amdgcn_s_barrier();
    // (7) restage cur for it+2 (drained by next iteration's step 3)
    if (it < 14) {
      stageK(cur, kvbase + (it + 2) * 64);
      stageV(cur, kvbase + (it + 2) * 64);
    }
  }

  // ---- merge halves through reused LDS ----
  float* shO = (float*)smem;             // [4][64][33]
  float* shML = (float*)(smem + 33792);  // [4][64][2]
  if (half == 1) {
    float* o = shO + (size_t)(wq * 64 + lane) * 33;
#pragma unroll
    for (int i = 0; i < 16; i++) { o[i] = o0[i]; o[16 + i] = o1[i]; }
    shML[(wq * 64 + lane) * 2] = mrow;
    shML[(wq * 64 + lane) * 2 + 1] = lrow;
  }
  __syncthreads();
  if (half == 0) {
    const float* o = shO + (size_t)(wq * 64 + lane) * 33;
    const float mB = shML[(wq * 64 + lane) * 2];
    const float lB = shML[(wq * 64 + lane) * 2 + 1];
    const float M = fmaxf(mrow, mB);
    const float wA = fast_exp2(mrow - M), wB = fast_exp2(mB - M);
    const float inv = 1.f / (lrow * wA + lB * wB);
    const float fA = wA * inv, fB = wB * inv;

    // O[d][q]: lane q31 owns q-col; d = 8*j + 4*hi + r (o0), +32 (o1)
    bf16* obase = Op + ((size_t)(b * SEQ + qrow)) * EMBED + h * HD;
#pragma unroll
    for (int j = 0; j < 4; j++) {
      bf16x4 st;
#pragma unroll
      for (int r = 0; r < 4; r++)
        st[r] = (bf16)(o0[4 * j + r] * fA + o[4 * j + r] * fB);
      *(bf16x4*)(obase + 8 * j + 4 * hi) = st;
    }
#pragma unroll
    for (int j = 0; j < 4; j++) {
      bf16x4 st;
#pragma unroll
      for (int r = 0; r < 4; r++)
        st[r] = (bf16)(o1[4 * j + r] * fA + o[16 + 4 * j + r] * fB);
      *(bf16x4*)(obase + 32 + 8 * j + 4 * hi) = st;
    }
  }
}

// ---------------- launch ----------------
extern "C" void kernel_launch(void* const* d_in, const int* in_sizes, int n_in,
                              void* d_out, int out_size, void* d_ws, size_t ws_size,
                              hipStream_t stream) {
  const float* x     = (const float*)d_in[0];
  const float* q_w   = (const float*)d_in[1];
  const float* q_b   = (const float*)d_in[2];
  const float* k_w   = (const float*)d_in[3];
  const float* k_b   = (const float*)d_in[4];
  const float* v_w   = (const float*)d_in[5];
  const float* v_b   = (const float*)d_in[6];
  const float* phase = (const float*)d_in[7];
  const float* ent   = (const float*)d_in[8];
  const float* out_w = (const float*)d_in[9];
  const float* out_b = (const float*)d_in[10];
  float* out = (float*)d_out;

  char* ws = (char*)d_ws;
  bf16* xb    = (bf16*)(ws + 0);          // 8388608 B, [B,S,E] bf16; reused as attn out
  bf16* wtall = (bf16*)(ws + 8388608);    // 6291456 B, [3072][1024] bf16 (Qeff|K|V)
  bf16* wot   = (bf16*)(ws + 14680064);   // 2097152 B, out_w^T bf16
  float* beff = (float*)(ws + 16777216);  // 4096 B
  bf16* Qp    = (bf16*)(ws + 16781312);   // 8388608 B
  bf16* Kp    = (bf16*)(ws + 25169920);   // 8388608 B
  bf16* Vt    = (bf16*)(ws + 33558528);   // 8388608 B, [b,h,d,s]
  (void)in_sizes; (void)n_in; (void)out_size; (void)ws_size;

  prep_kernel<<<3088, 256, 0, stream>>>(x, q_w, q_b, k_w, v_w, out_w, ent, phase,
                                        xb, wtall, wot, beff);

  gemm_qkv_kernel<<<768, 256, 0, stream>>>(
      xb, wtall, beff, k_b, v_b, Qp, Kp, Vt);

  flash_attn_kernel<<<512, 512, 0, stream>>>(Qp, Kp, Vt, xb);

  gemm_out_kernel<<<512, 256, 0, stream>>>(xb, wot, out_b, out);
}